// Round 1
// baseline (516.121 us; speedup 1.0000x reference)
//
#include <hip/hip_runtime.h>

#define NN 100000
#define NE 200000
#define NG 5000
#define EPSI 1e-5f

// ---- workspace layout (floats) ----
constexpr long OFF_NORM = 0;                       // NN        (deg -> norm, zeroed)
constexpr long OFF_AGG1 = NN;                      // 32*NN     (agg1/out1/h1 in-place, zeroed)
constexpr long OFF_AGG2 = OFF_AGG1 + 32L * NN;     // 64*NN     (agg2/out2 in-place, zeroed)
constexpr long OFF_GSUM = OFF_AGG2 + 64L * NN;     // 64*NG     (zeroed)
constexpr long OFF_GCNT = OFF_GSUM + 64L * NG;     // NG        (zeroed)
constexpr long OFF_STAT = OFF_GCNT + NG;           // 512       (zeroed)
constexpr long ZERO_FLOATS = OFF_STAT + 512;       // ~10.03M floats = 40.1 MB

__global__ void k_deg(const int* __restrict__ ei, float* __restrict__ deg) {
    int e = blockIdx.x * blockDim.x + threadIdx.x;
    if (e < NE) atomicAdd(&deg[ei[e]], 1.0f);
}

__global__ void k_norm(float* __restrict__ deg) {
    int n = blockIdx.x * blockDim.x + threadIdx.x;
    if (n < NN) { float d = deg[n]; deg[n] = d > 0.f ? 1.f / d : 0.f; }
}

// Layer-1 edge messages: wave per edge; lane = (o in 0..31, i-half), weights in VGPRs.
__global__ void k_edge1(const int* __restrict__ ei, const float* __restrict__ ea,
                        const float* __restrict__ x, const float* __restrict__ We1,
                        const float* __restrict__ nrm, float* __restrict__ agg1) {
    const int lane = threadIdx.x & 63;
    const int o = lane & 31;
    const int sub = lane >> 5;
    float w[8][8];
    {
        const float* wp = We1 + (o * 16 + sub * 8) * 8;
        #pragma unroll
        for (int i = 0; i < 8; ++i)
            #pragma unroll
            for (int f = 0; f < 8; ++f) w[i][f] = wp[i * 8 + f];
    }
    int gw = (blockIdx.x * blockDim.x + threadIdx.x) >> 6;
    int nw = (gridDim.x * blockDim.x) >> 6;
    for (int e = gw; e < NE; e += nw) {
        int s = ei[e];
        int d = ei[NE + e];
        float nv = nrm[s];
        const float* eap = ea + e * 8;
        const float* xp  = x + s * 16 + sub * 8;
        float ev[8], xv[8];
        #pragma unroll
        for (int f = 0; f < 8; ++f) ev[f] = eap[f];
        #pragma unroll
        for (int i = 0; i < 8; ++i) xv[i] = xp[i];
        float p = 0.f;
        #pragma unroll
        for (int i = 0; i < 8; ++i) {
            float t = 0.f;
            #pragma unroll
            for (int f = 0; f < 8; ++f) t += w[i][f] * ev[f];
            p += t * xv[i];
        }
        p += __shfl_xor(p, 32);
        if (sub == 0) atomicAdd(&agg1[d * 32 + o], p * nv);
    }
}

// Layer-2 edge messages: block = 4 waves; wave w owns i-range [8w,8w+8); batch 4 edges.
__global__ void k_edge2(const int* __restrict__ ei, const float* __restrict__ ea,
                        const float* __restrict__ h1, const float* __restrict__ We2,
                        const float* __restrict__ nrm, float* __restrict__ agg2) {
    const int o = threadIdx.x & 63;
    const int w = threadIdx.x >> 6;
    float wr[8][8];
    {
        const float* wp = We2 + (o * 32 + w * 8) * 8;
        #pragma unroll
        for (int i = 0; i < 8; ++i)
            #pragma unroll
            for (int f = 0; f < 8; ++f) wr[i][f] = wp[i * 8 + f];
    }
    __shared__ float part[4][4][64];  // [edge_in_batch][wave][o] -> conflict-free
    for (long base = blockIdx.x * 4L; base < NE; base += (long)gridDim.x * 4L) {
        #pragma unroll
        for (int eb = 0; eb < 4; ++eb) {
            long e = base + eb;
            float p = 0.f;
            if (e < NE) {
                int s = ei[e];
                const float* hp  = h1 + (long)s * 32 + w * 8;
                const float* eap = ea + e * 8;
                float ev[8], hv[8];
                #pragma unroll
                for (int f = 0; f < 8; ++f) ev[f] = eap[f];
                #pragma unroll
                for (int i = 0; i < 8; ++i) hv[i] = hp[i];
                #pragma unroll
                for (int i = 0; i < 8; ++i) {
                    float t = 0.f;
                    #pragma unroll
                    for (int f = 0; f < 8; ++f) t += wr[i][f] * ev[f];
                    p += t * hv[i];
                }
            }
            part[eb][w][o] = p;
        }
        __syncthreads();
        {
            int eb = w;
            long e = base + eb;
            if (e < NE) {
                float m = part[eb][0][o] + part[eb][1][o] + part[eb][2][o] + part[eb][3][o];
                int s = ei[e];
                int d = ei[NE + e];
                atomicAdd(&agg2[(long)d * 64 + o], m * nrm[s]);
            }
        }
        __syncthreads();
    }
}

// out1 = agg1 + b1 + x @ Wr1.T   (in place on agg1); lane owns channel o, 2 nodes/wave.
__global__ void k_node1(const float* __restrict__ x, const float* __restrict__ Wr1,
                        const float* __restrict__ b1, float* __restrict__ out1) {
    const int lane = threadIdx.x & 63;
    const int o = lane & 31;
    const int sub = lane >> 5;
    float w[16];
    #pragma unroll
    for (int i = 0; i < 16; ++i) w[i] = Wr1[o * 16 + i];
    float bias = b1[o];
    int gw = (blockIdx.x * blockDim.x + threadIdx.x) >> 6;
    int nw = (gridDim.x * blockDim.x) >> 6;
    for (int n0 = gw * 2; n0 < NN; n0 += nw * 2) {
        int n = n0 + sub;
        if (n < NN) {
            const float* xp = x + n * 16;
            float acc = out1[(long)n * 32 + o] + bias;
            #pragma unroll
            for (int i = 0; i < 16; ++i) acc += xp[i] * w[i];
            out1[(long)n * 32 + o] = acc;
        }
    }
}

// out2 = agg2 + b2 + h1 @ Wr2.T (in place on agg2); lane owns channel o, wave per node.
__global__ void k_node2(const float* __restrict__ h1, const float* __restrict__ Wr2,
                        const float* __restrict__ b2, float* __restrict__ out2) {
    const int o = threadIdx.x & 63;
    float w[32];
    #pragma unroll
    for (int i = 0; i < 32; ++i) w[i] = Wr2[o * 32 + i];
    float bias = b2[o];
    int gw = (blockIdx.x * blockDim.x + threadIdx.x) >> 6;
    int nw = (gridDim.x * blockDim.x) >> 6;
    for (int n = gw; n < NN; n += nw) {
        const float* hp = h1 + (long)n * 32;
        float acc = out2[(long)n * 64 + o] + bias;
        #pragma unroll
        for (int i = 0; i < 32; ++i) acc += hp[i] * w[i];
        out2[(long)n * 64 + o] = acc;
    }
}

template <int C>
__global__ void k_colstats(const float* __restrict__ v, float* __restrict__ sum,
                           float* __restrict__ ssq) {
    constexpr int RPB = 256 / C;
    const int c = threadIdx.x % C;
    const int r = threadIdx.x / C;
    float s = 0.f, q = 0.f;
    for (int n = blockIdx.x * RPB + r; n < NN; n += gridDim.x * RPB) {
        float val = v[(long)n * C + c];
        s += val; q += val * val;
    }
    __shared__ float ls[256], lq[256];
    ls[threadIdx.x] = s; lq[threadIdx.x] = q;
    __syncthreads();
    if (threadIdx.x < C) {
        float ts = 0.f, tq = 0.f;
        #pragma unroll
        for (int k = 0; k < RPB; ++k) { ts += ls[c + k * C]; tq += lq[c + k * C]; }
        atomicAdd(&sum[c], ts);
        atomicAdd(&ssq[c], tq);
    }
}

__global__ void k_fin(int C, const float* __restrict__ sum, const float* __restrict__ ssq,
                      const float* __restrict__ g, const float* __restrict__ be,
                      float* __restrict__ scale, float* __restrict__ shift) {
    int c = threadIdx.x;
    if (c < C) {
        float mu  = sum[c] / (float)NN;
        float var = ssq[c] / (float)NN - mu * mu;
        float rs  = rsqrtf(var + EPSI);
        float sc  = rs * g[c];
        scale[c] = sc;
        shift[c] = be[c] - mu * sc;
    }
}

__global__ void k_bnrelu32(const float* __restrict__ in, const float* __restrict__ scale,
                           const float* __restrict__ shift, float* __restrict__ outp) {
    long t = (long)blockIdx.x * blockDim.x + threadIdx.x;
    if (t < 32L * NN) {
        int c = (int)(t & 31);
        float v = in[t] * scale[c] + shift[c];
        outp[t] = v > 0.f ? v : 0.f;
    }
}

// bn2 + relu + mean-pool scatter (sums); counts in k_cnt.
__global__ void k_pool(const float* __restrict__ out2, const int* __restrict__ batch,
                       const float* __restrict__ scale, const float* __restrict__ shift,
                       float* __restrict__ gsum) {
    long t = (long)blockIdx.x * blockDim.x + threadIdx.x;
    if (t < 64L * NN) {
        int c = (int)(t & 63);
        int n = (int)(t >> 6);
        float v = out2[t] * scale[c] + shift[c];
        v = v > 0.f ? v : 0.f;
        atomicAdd(&gsum[(long)batch[n] * 64 + c], v);
    }
}

__global__ void k_cnt(const int* __restrict__ batch, float* __restrict__ gcnt) {
    int n = blockIdx.x * blockDim.x + threadIdx.x;
    if (n < NN) atomicAdd(&gcnt[batch[n]], 1.0f);
}

// Wave per graph: pooled(64) -> fc1(128, relu) -> fc2(128) -> split mu/log_sigma.
// All cross-lane via __shfl (no LDS, no block sync).
__global__ void k_fc(const float* __restrict__ gsum, const float* __restrict__ gcnt,
                     const float* __restrict__ Wf1, const float* __restrict__ bf1,
                     const float* __restrict__ Wf2, const float* __restrict__ bf2,
                     float* __restrict__ outp) {
    const int lane = threadIdx.x & 63;
    int gw = (blockIdx.x * blockDim.x + threadIdx.x) >> 6;
    int nw = (gridDim.x * blockDim.x) >> 6;
    for (int g = gw; g < NG; g += nw) {
        float cnt = gcnt[g];
        float rc = 1.f / (cnt > 1.f ? cnt : 1.f);
        float pl = gsum[(long)g * 64 + lane] * rc;
        float f1a = bf1[lane], f1b = bf1[lane + 64];
        const float* w1a = Wf1 + lane * 64;
        const float* w1b = Wf1 + (lane + 64) * 64;
        #pragma unroll 8
        for (int i = 0; i < 64; ++i) {
            float pv = __shfl(pl, i);
            f1a += pv * w1a[i];
            f1b += pv * w1b[i];
        }
        f1a = f1a > 0.f ? f1a : 0.f;
        f1b = f1b > 0.f ? f1b : 0.f;
        float oa = bf2[lane], ob = bf2[lane + 64];
        const float* w2a = Wf2 + lane * 128;
        const float* w2b = Wf2 + (lane + 64) * 128;
        #pragma unroll 8
        for (int i = 0; i < 64; ++i) {
            float va = __shfl(f1a, i);
            float vb = __shfl(f1b, i);
            oa += va * w2a[i] + vb * w2a[64 + i];
            ob += va * w2b[i] + vb * w2b[64 + i];
        }
        outp[(long)g * 64 + lane] = oa;                       // mu_z
        outp[(long)NG * 64 + (long)g * 64 + lane] = ob;       // log_sigma
    }
}

extern "C" void kernel_launch(void* const* d_in, const int* in_sizes, int n_in,
                              void* d_out, int out_size, void* d_ws, size_t ws_size,
                              hipStream_t stream) {
    const float* x   = (const float*)d_in[0];
    const int*   ei  = (const int*)d_in[1];
    const float* ea  = (const float*)d_in[2];
    const int*   bat = (const int*)d_in[3];
    const float* We1 = (const float*)d_in[4];
    const float* b1  = (const float*)d_in[5];
    const float* Wr1 = (const float*)d_in[6];
    const float* g1  = (const float*)d_in[7];
    const float* be1 = (const float*)d_in[8];
    const float* We2 = (const float*)d_in[9];
    const float* b2  = (const float*)d_in[10];
    const float* Wr2 = (const float*)d_in[11];
    const float* g2  = (const float*)d_in[12];
    const float* be2 = (const float*)d_in[13];
    const float* Wf1 = (const float*)d_in[14];
    const float* bf1 = (const float*)d_in[15];
    const float* Wf2 = (const float*)d_in[16];
    const float* bf2 = (const float*)d_in[17];
    float* out = (float*)d_out;
    float* ws  = (float*)d_ws;

    float* nrm   = ws + OFF_NORM;
    float* agg1  = ws + OFF_AGG1;   // -> out1 -> h1 (in place)
    float* agg2  = ws + OFF_AGG2;   // -> out2 (in place)
    float* gsum  = ws + OFF_GSUM;
    float* gcnt  = ws + OFF_GCNT;
    float* st    = ws + OFF_STAT;
    float* sums1 = st;        float* ssq1 = st + 32;
    float* sums2 = st + 64;   float* ssq2 = st + 128;
    float* sc1   = st + 192;  float* sh1  = st + 224;
    float* sc2   = st + 256;  float* sh2  = st + 320;

    hipMemsetAsync(d_ws, 0, (size_t)ZERO_FLOATS * sizeof(float), stream);

    k_deg<<<(NE + 255) / 256, 256, 0, stream>>>(ei, nrm);
    k_norm<<<(NN + 255) / 256, 256, 0, stream>>>(nrm);

    k_edge1<<<1024, 256, 0, stream>>>(ei, ea, x, We1, nrm, agg1);
    k_node1<<<1024, 256, 0, stream>>>(x, Wr1, b1, agg1);
    k_colstats<32><<<1024, 256, 0, stream>>>(agg1, sums1, ssq1);
    k_fin<<<1, 64, 0, stream>>>(32, sums1, ssq1, g1, be1, sc1, sh1);
    k_bnrelu32<<<(int)((32L * NN + 255) / 256), 256, 0, stream>>>(agg1, sc1, sh1, agg1);

    k_edge2<<<1024, 256, 0, stream>>>(ei, ea, agg1, We2, nrm, agg2);
    k_node2<<<1024, 256, 0, stream>>>(agg1, Wr2, b2, agg2);
    k_colstats<64><<<1024, 256, 0, stream>>>(agg2, sums2, ssq2);
    k_fin<<<1, 64, 0, stream>>>(64, sums2, ssq2, g2, be2, sc2, sh2);

    k_pool<<<(int)((64L * NN + 255) / 256), 256, 0, stream>>>(agg2, bat, sc2, sh2, gsum);
    k_cnt<<<(NN + 255) / 256, 256, 0, stream>>>(bat, gcnt);

    k_fc<<<1250, 256, 0, stream>>>(gsum, gcnt, Wf1, bf1, Wf2, bf2, out);
}

// Round 2
// 463.329 us; speedup vs baseline: 1.1139x; 1.1139x over previous
//
#include <hip/hip_runtime.h>

#define NN 100000
#define NE 200000
#define NG 5000
#define EPSI 1e-5f

using short8 = __attribute__((ext_vector_type(8))) short;
using f32x4  = __attribute__((ext_vector_type(4))) float;

static __device__ inline short bfbits(float f) {
    __bf16 b = (__bf16)f;
    return __builtin_bit_cast(short, b);
}

// ---- workspace layout (floats) ----
constexpr long OFF_NORM = 0;                       // NN        (deg -> norm, zeroed)
constexpr long OFF_AGG1 = NN;                      // 32*NN     (agg1/out1/h1 in-place, zeroed)
constexpr long OFF_AGG2 = OFF_AGG1 + 32L * NN;     // 64*NN     (agg2/out2 in-place, zeroed)
constexpr long OFF_GSUM = OFF_AGG2 + 64L * NN;     // 64*NG     (zeroed)
constexpr long OFF_GCNT = OFF_GSUM + 64L * NG;     // NG        (zeroed)
constexpr long OFF_STAT = OFF_GCNT + NG;           // 512       (zeroed)
constexpr long ZERO_FLOATS = OFF_STAT + 512;       // ~10.03M floats = 40.1 MB

__global__ void k_deg(const int* __restrict__ ei, float* __restrict__ deg) {
    int e = blockIdx.x * blockDim.x + threadIdx.x;
    if (e < NE) atomicAdd(&deg[ei[e]], 1.0f);
}

__global__ void k_norm(float* __restrict__ deg) {
    int n = blockIdx.x * blockDim.x + threadIdx.x;
    if (n < NN) { float d = deg[n]; deg[n] = d > 0.f ? 1.f / d : 0.f; }
}

// ---------------------------------------------------------------------------
// Layer-1 edge messages via MFMA: U[e, i*8+f] = norm[s]*x[src,i]*ea[e,f],
// msg = U @ W1flat.T  (K=128, N=32).  Wave handles 16 edges x 16 out-cols.
// A-fragment built in registers: for K-step kk, a[j] = hv[kk]*ea[j].
// ---------------------------------------------------------------------------
__global__ void __launch_bounds__(256) k_edge1_mfma(
    const int* __restrict__ ei, const float* __restrict__ ea,
    const float* __restrict__ x, const float* __restrict__ We1,
    const float* __restrict__ nrm, float* __restrict__ agg1)
{
    const int lane = threadIdx.x & 63;
    const int wid  = threadIdx.x >> 6;
    const int c = lane & 15;   // A-row (edge) / D-col (out channel within tile)
    const int q = lane >> 4;   // k-quad
    const int gw = blockIdx.x * 4 + wid;
    const int ntile = gw & 1;          // out-col tile (0..1)
    const int grp   = gw >> 1;         // 16-edge group (0..12499)
    if (grp >= 12500) return;

    // B[k, col] = We1[col*128 + k]; lane holds col = ntile*16+c, k = q*8+kk*32+j
    short8 bfr[4];
    {
        const float* wrow = We1 + (ntile * 16 + c) * 128 + q * 8;
        #pragma unroll
        for (int kk = 0; kk < 4; ++kk) {
            const float* p = wrow + kk * 32;
            #pragma unroll
            for (int j = 0; j < 8; ++j) bfr[kk][j] = bfbits(p[j]);
        }
    }

    const long e0 = (long)grp * 16;
    const long e  = e0 + c;
    const int  s  = ei[e];
    const float nv = nrm[s];
    float ev[8];
    {
        const float* p = ea + e * 8;
        #pragma unroll
        for (int j = 0; j < 8; ++j) ev[j] = p[j];
    }
    // hv[kk] = x[s*16 + kk*4 + q] * nv   (i = k>>3 = kk*4+q)
    float hv[4];
    {
        const float* hp = x + (long)s * 16 + q;
        #pragma unroll
        for (int kk = 0; kk < 4; ++kk) hv[kk] = hp[kk * 4] * nv;
    }
    f32x4 acc = {0.f, 0.f, 0.f, 0.f};
    #pragma unroll
    for (int kk = 0; kk < 4; ++kk) {
        short8 afr;
        #pragma unroll
        for (int j = 0; j < 8; ++j) afr[j] = bfbits(hv[kk] * ev[j]);
        acc = __builtin_amdgcn_mfma_f32_16x16x32_bf16(afr, bfr[kk], acc, 0, 0, 0);
    }
    // D: row m = q*4+t (edge e0+m), col = ntile*16+c
    #pragma unroll
    for (int t = 0; t < 4; ++t) {
        int m = q * 4 + t;
        int d = ei[NE + e0 + m];
        atomicAdd(&agg1[(long)d * 32 + ntile * 16 + c], acc[t]);
    }
}

// ---------------------------------------------------------------------------
// Layer-2 edge messages via MFMA: K=256, N=64. Wave: 16 edges x 16 out-cols.
// ---------------------------------------------------------------------------
__global__ void __launch_bounds__(256) k_edge2_mfma(
    const int* __restrict__ ei, const float* __restrict__ ea,
    const float* __restrict__ h1, const float* __restrict__ We2,
    const float* __restrict__ nrm, float* __restrict__ agg2)
{
    const int lane = threadIdx.x & 63;
    const int wid  = threadIdx.x >> 6;
    const int c = lane & 15;
    const int q = lane >> 4;
    const int gw = blockIdx.x * 4 + wid;
    const int ntile = gw & 3;          // out-col tile (0..3)
    const int grp   = gw >> 2;         // 16-edge group (0..12499)
    if (grp >= 12500) return;

    // B[k, col] = We2[col*256 + k]
    short8 bfr[8];
    {
        const float* wrow = We2 + (ntile * 16 + c) * 256 + q * 8;
        #pragma unroll
        for (int kk = 0; kk < 8; ++kk) {
            const float* p = wrow + kk * 32;
            #pragma unroll
            for (int j = 0; j < 8; ++j) bfr[kk][j] = bfbits(p[j]);
        }
    }

    const long e0 = (long)grp * 16;
    const long e  = e0 + c;
    const int  s  = ei[e];
    const float nv = nrm[s];
    float ev[8];
    {
        const float* p = ea + e * 8;
        #pragma unroll
        for (int j = 0; j < 8; ++j) ev[j] = p[j];
    }
    // hv[kk] = h1[s*32 + kk*4 + q] * nv
    float hv[8];
    {
        const float* hp = h1 + (long)s * 32 + q;
        #pragma unroll
        for (int kk = 0; kk < 8; ++kk) hv[kk] = hp[kk * 4] * nv;
    }
    f32x4 acc = {0.f, 0.f, 0.f, 0.f};
    #pragma unroll
    for (int kk = 0; kk < 8; ++kk) {
        short8 afr;
        #pragma unroll
        for (int j = 0; j < 8; ++j) afr[j] = bfbits(hv[kk] * ev[j]);
        acc = __builtin_amdgcn_mfma_f32_16x16x32_bf16(afr, bfr[kk], acc, 0, 0, 0);
    }
    #pragma unroll
    for (int t = 0; t < 4; ++t) {
        int m = q * 4 + t;
        int d = ei[NE + e0 + m];
        atomicAdd(&agg2[(long)d * 64 + ntile * 16 + c], acc[t]);
    }
}

// out1 = agg1 + b1 + x @ Wr1.T   (in place on agg1); lane owns channel o, 2 nodes/wave.
__global__ void k_node1(const float* __restrict__ x, const float* __restrict__ Wr1,
                        const float* __restrict__ b1, float* __restrict__ out1) {
    const int lane = threadIdx.x & 63;
    const int o = lane & 31;
    const int sub = lane >> 5;
    float w[16];
    #pragma unroll
    for (int i = 0; i < 16; ++i) w[i] = Wr1[o * 16 + i];
    float bias = b1[o];
    int gw = (blockIdx.x * blockDim.x + threadIdx.x) >> 6;
    int nw = (gridDim.x * blockDim.x) >> 6;
    for (int n0 = gw * 2; n0 < NN; n0 += nw * 2) {
        int n = n0 + sub;
        if (n < NN) {
            const float* xp = x + n * 16;
            float acc = out1[(long)n * 32 + o] + bias;
            #pragma unroll
            for (int i = 0; i < 16; ++i) acc += xp[i] * w[i];
            out1[(long)n * 32 + o] = acc;
        }
    }
}

// out2 = agg2 + b2 + h1 @ Wr2.T (in place on agg2); lane owns channel o, wave per node.
__global__ void k_node2(const float* __restrict__ h1, const float* __restrict__ Wr2,
                        const float* __restrict__ b2, float* __restrict__ out2) {
    const int o = threadIdx.x & 63;
    float w[32];
    #pragma unroll
    for (int i = 0; i < 32; ++i) w[i] = Wr2[o * 32 + i];
    float bias = b2[o];
    int gw = (blockIdx.x * blockDim.x + threadIdx.x) >> 6;
    int nw = (gridDim.x * blockDim.x) >> 6;
    for (int n = gw; n < NN; n += nw) {
        const float* hp = h1 + (long)n * 32;
        float acc = out2[(long)n * 64 + o] + bias;
        #pragma unroll
        for (int i = 0; i < 32; ++i) acc += hp[i] * w[i];
        out2[(long)n * 64 + o] = acc;
    }
}

template <int C>
__global__ void k_colstats(const float* __restrict__ v, float* __restrict__ sum,
                           float* __restrict__ ssq) {
    constexpr int RPB = 256 / C;
    const int c = threadIdx.x % C;
    const int r = threadIdx.x / C;
    float s = 0.f, q = 0.f;
    for (int n = blockIdx.x * RPB + r; n < NN; n += gridDim.x * RPB) {
        float val = v[(long)n * C + c];
        s += val; q += val * val;
    }
    __shared__ float ls[256], lq[256];
    ls[threadIdx.x] = s; lq[threadIdx.x] = q;
    __syncthreads();
    if (threadIdx.x < C) {
        float ts = 0.f, tq = 0.f;
        #pragma unroll
        for (int k = 0; k < RPB; ++k) { ts += ls[c + k * C]; tq += lq[c + k * C]; }
        atomicAdd(&sum[c], ts);
        atomicAdd(&ssq[c], tq);
    }
}

__global__ void k_fin(int C, const float* __restrict__ sum, const float* __restrict__ ssq,
                      const float* __restrict__ g, const float* __restrict__ be,
                      float* __restrict__ scale, float* __restrict__ shift) {
    int c = threadIdx.x;
    if (c < C) {
        float mu  = sum[c] / (float)NN;
        float var = ssq[c] / (float)NN - mu * mu;
        float rs  = rsqrtf(var + EPSI);
        float sc  = rs * g[c];
        scale[c] = sc;
        shift[c] = be[c] - mu * sc;
    }
}

__global__ void k_bnrelu32(const float* __restrict__ in, const float* __restrict__ scale,
                           const float* __restrict__ shift, float* __restrict__ outp) {
    long t = (long)blockIdx.x * blockDim.x + threadIdx.x;
    if (t < 32L * NN) {
        int c = (int)(t & 31);
        float v = in[t] * scale[c] + shift[c];
        outp[t] = v > 0.f ? v : 0.f;
    }
}

// bn2 + relu + mean-pool scatter. batch is SORTED -> accumulate 4 consecutive
// nodes per thread, flush on graph change (~4x fewer atomics).
__global__ void k_pool(const float* __restrict__ out2, const int* __restrict__ batch,
                       const float* __restrict__ scale, const float* __restrict__ shift,
                       float* __restrict__ gsum) {
    long t = (long)blockIdx.x * blockDim.x + threadIdx.x;
    int c = (int)(t & 63);
    long n0 = (t >> 6) * 4;
    if (n0 >= NN) return;
    float sc = scale[c], sh = shift[c];
    float acc = 0.f;
    int gprev = batch[n0];
    #pragma unroll
    for (int k = 0; k < 4; ++k) {
        long n = n0 + k;
        if (n >= NN) break;
        int g = batch[n];
        float v = out2[n * 64 + c] * sc + sh;
        v = v > 0.f ? v : 0.f;
        if (g != gprev) {
            atomicAdd(&gsum[(long)gprev * 64 + c], acc);
            acc = 0.f; gprev = g;
        }
        acc += v;
    }
    atomicAdd(&gsum[(long)gprev * 64 + c], acc);
}

__global__ void k_cnt(const int* __restrict__ batch, float* __restrict__ gcnt) {
    int n = blockIdx.x * blockDim.x + threadIdx.x;
    if (n < NN) atomicAdd(&gcnt[batch[n]], 1.0f);
}

// Wave per graph: pooled(64) -> fc1(128, relu) -> fc2(128) -> split mu/log_sigma.
__global__ void k_fc(const float* __restrict__ gsum, const float* __restrict__ gcnt,
                     const float* __restrict__ Wf1, const float* __restrict__ bf1,
                     const float* __restrict__ Wf2, const float* __restrict__ bf2,
                     float* __restrict__ outp) {
    const int lane = threadIdx.x & 63;
    int gw = (blockIdx.x * blockDim.x + threadIdx.x) >> 6;
    int nw = (gridDim.x * blockDim.x) >> 6;
    for (int g = gw; g < NG; g += nw) {
        float cnt = gcnt[g];
        float rc = 1.f / (cnt > 1.f ? cnt : 1.f);
        float pl = gsum[(long)g * 64 + lane] * rc;
        float f1a = bf1[lane], f1b = bf1[lane + 64];
        const float* w1a = Wf1 + lane * 64;
        const float* w1b = Wf1 + (lane + 64) * 64;
        #pragma unroll 8
        for (int i = 0; i < 64; ++i) {
            float pv = __shfl(pl, i);
            f1a += pv * w1a[i];
            f1b += pv * w1b[i];
        }
        f1a = f1a > 0.f ? f1a : 0.f;
        f1b = f1b > 0.f ? f1b : 0.f;
        float oa = bf2[lane], ob = bf2[lane + 64];
        const float* w2a = Wf2 + lane * 128;
        const float* w2b = Wf2 + (lane + 64) * 128;
        #pragma unroll 8
        for (int i = 0; i < 64; ++i) {
            float va = __shfl(f1a, i);
            float vb = __shfl(f1b, i);
            oa += va * w2a[i] + vb * w2a[64 + i];
            ob += va * w2b[i] + vb * w2b[64 + i];
        }
        outp[(long)g * 64 + lane] = oa;                       // mu_z
        outp[(long)NG * 64 + (long)g * 64 + lane] = ob;       // log_sigma
    }
}

extern "C" void kernel_launch(void* const* d_in, const int* in_sizes, int n_in,
                              void* d_out, int out_size, void* d_ws, size_t ws_size,
                              hipStream_t stream) {
    const float* x   = (const float*)d_in[0];
    const int*   ei  = (const int*)d_in[1];
    const float* ea  = (const float*)d_in[2];
    const int*   bat = (const int*)d_in[3];
    const float* We1 = (const float*)d_in[4];
    const float* b1  = (const float*)d_in[5];
    const float* Wr1 = (const float*)d_in[6];
    const float* g1  = (const float*)d_in[7];
    const float* be1 = (const float*)d_in[8];
    const float* We2 = (const float*)d_in[9];
    const float* b2  = (const float*)d_in[10];
    const float* Wr2 = (const float*)d_in[11];
    const float* g2  = (const float*)d_in[12];
    const float* be2 = (const float*)d_in[13];
    const float* Wf1 = (const float*)d_in[14];
    const float* bf1 = (const float*)d_in[15];
    const float* Wf2 = (const float*)d_in[16];
    const float* bf2 = (const float*)d_in[17];
    float* out = (float*)d_out;
    float* ws  = (float*)d_ws;

    float* nrm   = ws + OFF_NORM;
    float* agg1  = ws + OFF_AGG1;   // -> out1 -> h1 (in place)
    float* agg2  = ws + OFF_AGG2;   // -> out2 (in place)
    float* gsum  = ws + OFF_GSUM;
    float* gcnt  = ws + OFF_GCNT;
    float* st    = ws + OFF_STAT;
    float* sums1 = st;        float* ssq1 = st + 32;
    float* sums2 = st + 64;   float* ssq2 = st + 128;
    float* sc1   = st + 192;  float* sh1  = st + 224;
    float* sc2   = st + 256;  float* sh2  = st + 320;

    hipMemsetAsync(d_ws, 0, (size_t)ZERO_FLOATS * sizeof(float), stream);

    k_deg<<<(NE + 255) / 256, 256, 0, stream>>>(ei, nrm);
    k_norm<<<(NN + 255) / 256, 256, 0, stream>>>(nrm);

    // 12500 groups x 2 ntile-waves = 25000 waves = 6250 blocks
    k_edge1_mfma<<<6250, 256, 0, stream>>>(ei, ea, x, We1, nrm, agg1);
    k_node1<<<1024, 256, 0, stream>>>(x, Wr1, b1, agg1);
    k_colstats<32><<<1024, 256, 0, stream>>>(agg1, sums1, ssq1);
    k_fin<<<1, 64, 0, stream>>>(32, sums1, ssq1, g1, be1, sc1, sh1);
    k_bnrelu32<<<(int)((32L * NN + 255) / 256), 256, 0, stream>>>(agg1, sc1, sh1, agg1);

    // 12500 groups x 4 ntile-waves = 50000 waves = 12500 blocks
    k_edge2_mfma<<<12500, 256, 0, stream>>>(ei, ea, agg1, We2, nrm, agg2);
    k_node2<<<1024, 256, 0, stream>>>(agg1, Wr2, b2, agg2);
    k_colstats<64><<<1024, 256, 0, stream>>>(agg2, sums2, ssq2);
    k_fin<<<1, 64, 0, stream>>>(64, sums2, ssq2, g2, be2, sc2, sh2);

    k_pool<<<6250, 256, 0, stream>>>(agg2, bat, sc2, sh2, gsum);
    k_cnt<<<(NN + 255) / 256, 256, 0, stream>>>(bat, gcnt);

    k_fc<<<1250, 256, 0, stream>>>(gsum, gcnt, Wf1, bf1, Wf2, bf2, out);
}